// Round 1
// baseline (1659.062 us; speedup 1.0000x reference)
//
#include <hip/hip_runtime.h>
#include <cstddef>
#include <cstdint>

// Problem constants: B=2, N=2048, DIM=512, H=8, DH=64, K=32, SCALE=1/8
#define SEQ_N  2048
#define NHEAD  8
#define DHEAD  64
#define NMEM   32
#define SCALE_F 0.125f
#define NEG_INF -3.0e38f

__device__ __forceinline__ float wred_max(float v) {
#pragma unroll
  for (int o = 32; o > 0; o >>= 1) v = fmaxf(v, __shfl_xor(v, o));
  return v;
}
__device__ __forceinline__ float wred_sum(float v) {
#pragma unroll
  for (int o = 32; o > 0; o >>= 1) v += __shfl_xor(v, o);
  return v;
}

// ---------------------------------------------------------------------------
// Generic 64x64-tile f32 GEMM, 256 threads, 4x4 microtile per thread.
// MODE 0: C = x@Wq written as q[(b,h,i,d)]  (rows=b*2048+i, cols=h*64+d)
// MODE 1: C = x@Wkv split: cols 0..63 -> k[r*64+c], cols 64..127 -> v[r*64+c-64]
// MODE 2: C0[r*512+c] = acc + bias[c]
// ---------------------------------------------------------------------------
template <int MODE>
__global__ __launch_bounds__(256) void gemm64(
    const float* __restrict__ A, const float* __restrict__ Bw,
    float* __restrict__ C0, float* __restrict__ C1,
    const float* __restrict__ bias, int Kdim, int Ncols) {
  __shared__ float sA[64][17];
  __shared__ float sB[16][64];
  const int tid = threadIdx.x;
  const int tx = tid & 15, ty = tid >> 4;
  const int rowBase = blockIdx.x * 64, colBase = blockIdx.y * 64;
  float acc[4][4] = {};

  for (int k0 = 0; k0 < Kdim; k0 += 16) {
    {
      int r = tid >> 2, ks = (tid & 3) * 4;
      float4 a4 = *(const float4*)(A + (size_t)(rowBase + r) * Kdim + k0 + ks);
      sA[r][ks + 0] = a4.x; sA[r][ks + 1] = a4.y;
      sA[r][ks + 2] = a4.z; sA[r][ks + 3] = a4.w;
    }
#pragma unroll
    for (int it = 0; it < 4; ++it) {
      int kk = (tid >> 6) + it * 4, c = tid & 63;
      sB[kk][c] = Bw[(size_t)(k0 + kk) * Ncols + colBase + c];
    }
    __syncthreads();
#pragma unroll
    for (int kk = 0; kk < 16; ++kk) {
      float av[4];
#pragma unroll
      for (int u = 0; u < 4; ++u) av[u] = sA[ty * 4 + u][kk];
      float4 b4 = *(const float4*)&sB[kk][tx * 4];
#pragma unroll
      for (int u = 0; u < 4; ++u) {
        acc[u][0] += av[u] * b4.x; acc[u][1] += av[u] * b4.y;
        acc[u][2] += av[u] * b4.z; acc[u][3] += av[u] * b4.w;
      }
    }
    __syncthreads();
  }

#pragma unroll
  for (int ri = 0; ri < 4; ++ri) {
    int r = rowBase + ty * 4 + ri;
#pragma unroll
    for (int ci = 0; ci < 4; ++ci) {
      int c = colBase + tx * 4 + ci;
      float val = acc[ri][ci];
      if (MODE == 0) {
        int b = r >> 11, i = r & 2047, h = c >> 6, d = c & 63;
        C0[(((size_t)(b * NHEAD + h)) * SEQ_N + i) * DHEAD + d] = val;
      } else if (MODE == 1) {
        if (c < DHEAD) C0[(size_t)r * DHEAD + c] = val;
        else           C1[(size_t)r * DHEAD + (c - DHEAD)] = val;
      } else {
        C0[(size_t)r * 512 + c] = val + bias[c];
      }
    }
  }
}

// ---------------------------------------------------------------------------
// Memory attention: one wave per (b,h,i) row. 33 keys (null + 32 mem keys).
// Lane j in [1,32] computes its key's dot; lane d gathers V coalesced.
// ---------------------------------------------------------------------------
__global__ __launch_bounds__(256) void mem_attn_kernel(
    const float* __restrict__ q, const float* __restrict__ mem_kv,
    const int* __restrict__ mem_mask, const float* __restrict__ null_k,
    const float* __restrict__ null_v, float* __restrict__ mem_out) {
  __shared__ float sq[4][64];
  const int w = threadIdx.x >> 6;
  const int lane = threadIdx.x & 63;
  const int row = blockIdx.x * 4 + w;  // 0 .. B*H*N-1 (q layout row)
  const float qv = q[(size_t)row * DHEAD + lane];
  sq[w][lane] = qv;
  __syncthreads();

  const float* mk = mem_kv + (size_t)row * (NMEM * 2 * DHEAD);  // row*4096

  // null-key sim (all lanes participate; result used on lane 0)
  float nullsim = wred_sum(qv * null_k[lane]) * SCALE_F;

  float sim = NEG_INF;
  if (lane == 0) {
    sim = nullsim;
  } else if (lane <= NMEM) {
    int j = lane - 1;
    const float4* kp = (const float4*)(mk + j * 2 * DHEAD);
    float s = 0.f;
#pragma unroll
    for (int d4 = 0; d4 < 16; ++d4) {
      float4 k4 = kp[d4];
      float4 q4 = *(const float4*)&sq[w][d4 * 4];
      s += k4.x * q4.x + k4.y * q4.y + k4.z * q4.z + k4.w * q4.w;
    }
    s *= SCALE_F;
    if (mem_mask[(size_t)row * NMEM + j] == 0) s = NEG_INF;
    sim = s;
  }

  float m = wred_max(sim);
  float p = __expf(sim - m);
  if (lane > NMEM) p = 0.f;
  float l = wred_sum(p);
  p /= l;

  float acc = __shfl(p, 0) * null_v[lane];
#pragma unroll
  for (int j = 0; j < NMEM; ++j) {
    float pj = __shfl(p, j + 1);
    acc += pj * mk[j * 2 * DHEAD + DHEAD + lane];
  }
  mem_out[(size_t)row * DHEAD + lane] = acc;
}

// ---------------------------------------------------------------------------
// Causal local attention (flash-style, f32 vector) + gated combine with mem.
// Block: 256 threads = 4 waves; block covers 16 consecutive query rows of one
// (b,h); each wave owns 4 rows. Key/value tiles of 64 staged in LDS (pad 65).
// Writes gated result to comb[(b*2048+i)*512 + h*64 + d].
// ---------------------------------------------------------------------------
__global__ __launch_bounds__(256) void local_attn_kernel(
    const float* __restrict__ q, const float* __restrict__ kg,
    const float* __restrict__ vg, const float* __restrict__ mem_out,
    const float* __restrict__ gate, float* __restrict__ comb) {
  __shared__ float sk[64 * 65];
  __shared__ float sv[64 * 65];
  __shared__ float sq[16][64];
  const int tid = threadIdx.x;
  const int w = tid >> 6, lane = tid & 63;
  const int bh = blockIdx.x >> 7;            // 16 (b,h) pairs, 128 blocks each
  const int ig = (blockIdx.x & 127) * 16;    // first query row of block
  const int b = bh >> 3, h = bh & 7;

  // load 16 q rows into LDS
#pragma unroll
  for (int it = 0; it < 4; ++it) {
    int idx = tid + it * 256;
    int r = idx >> 6, d = idx & 63;
    sq[r][d] = q[((size_t)bh * SEQ_N + ig + r) * DHEAD + d];
  }

  const int r0 = w * 4;                       // wave's first local row
  float m[4], l[4], acc[4], ps[4];
#pragma unroll
  for (int u = 0; u < 4; ++u) { m[u] = NEG_INF; l[u] = 0.f; acc[u] = 0.f; }
  const int imax = ig + r0 + 3;
  const int ntiles = (ig + 15) / 64 + 1;
  const float* kbase = kg + (size_t)b * SEQ_N * DHEAD;
  const float* vbase = vg + (size_t)b * SEQ_N * DHEAD;

  for (int t = 0; t < ntiles; ++t) {
    __syncthreads();
#pragma unroll
    for (int it = 0; it < 4; ++it) {
      int idx = tid + it * 256;
      int jj = idx >> 4, d4 = idx & 15;
      float4 k4 = *(const float4*)(kbase + ((size_t)(t * 64 + jj)) * DHEAD + d4 * 4);
      float4 v4 = *(const float4*)(vbase + ((size_t)(t * 64 + jj)) * DHEAD + d4 * 4);
      float* skp = &sk[jj * 65 + d4 * 4];
      skp[0] = k4.x; skp[1] = k4.y; skp[2] = k4.z; skp[3] = k4.w;
      float* svp = &sv[jj * 65 + d4 * 4];
      svp[0] = v4.x; svp[1] = v4.y; svp[2] = v4.z; svp[3] = v4.w;
    }
    __syncthreads();

    if (t * 64 <= imax) {                     // wave-uniform causal skip
      const int jglob = t * 64 + lane;        // this lane's key index
      float s[4] = {0.f, 0.f, 0.f, 0.f};
#pragma unroll
      for (int d4 = 0; d4 < 16; ++d4) {
        float k0v = sk[lane * 65 + d4 * 4 + 0];
        float k1v = sk[lane * 65 + d4 * 4 + 1];
        float k2v = sk[lane * 65 + d4 * 4 + 2];
        float k3v = sk[lane * 65 + d4 * 4 + 3];
#pragma unroll
        for (int u = 0; u < 4; ++u) {
          float4 q4 = *(const float4*)&sq[r0 + u][d4 * 4];
          s[u] += q4.x * k0v + q4.y * k1v + q4.z * k2v + q4.w * k3v;
        }
      }
#pragma unroll
      for (int u = 0; u < 4; ++u) {
        int iq = ig + r0 + u;
        float sim = (jglob <= iq) ? s[u] * SCALE_F : NEG_INF;
        float tm = wred_max(sim);
        float nm = fmaxf(m[u], tm);
        float p = __expf(sim - nm);
        float ts = wred_sum(p);
        float sc = __expf(m[u] - nm);
        l[u] = l[u] * sc + ts;
        acc[u] *= sc;
        m[u] = nm;
        ps[u] = p;
      }
#pragma unroll 16
      for (int j = 0; j < 64; ++j) {
        float vj = sv[j * 65 + lane];
#pragma unroll
        for (int u = 0; u < 4; ++u) {
          float pj = __shfl(ps[u], j);
          acc[u] += pj * vj;
        }
      }
    }
  }

  const float g = 1.f / (1.f + __expf(-gate[h]));
#pragma unroll
  for (int u = 0; u < 4; ++u) {
    int iq = ig + r0 + u;
    size_t gr = (size_t)bh * SEQ_N + iq;
    float localv = acc[u] / l[u];
    float memv = mem_out[gr * DHEAD + lane];
    comb[((size_t)(b * SEQ_N + iq)) * 512 + h * DHEAD + lane] =
        g * localv + (1.f - g) * memv;
  }
}

// ---------------------------------------------------------------------------
extern "C" void kernel_launch(void* const* d_in, const int* in_sizes, int n_in,
                              void* d_out, int out_size, void* d_ws, size_t ws_size,
                              hipStream_t stream) {
  const float* x        = (const float*)d_in[0];
  const float* mem_kv   = (const float*)d_in[1];
  const int*   mem_mask = (const int*)d_in[2];   // bool in ref; assumed int32 upload
  const float* Wq       = (const float*)d_in[3];
  const float* Wkv      = (const float*)d_in[4];
  const float* Wo       = (const float*)d_in[5];
  const float* bo       = (const float*)d_in[6];
  const float* null_k   = (const float*)d_in[7];
  const float* null_v   = (const float*)d_in[8];
  const float* gate     = (const float*)d_in[9];
  float* out = (float*)d_out;

  float* ws    = (float*)d_ws;
  float* q_ws  = ws;                       // (B,H,N,DH)   2,097,152 f32
  float* k_ws  = q_ws + 2097152;           // (B,N,DH)       262,144
  float* v_ws  = k_ws + 262144;            // (B,N,DH)       262,144
  float* mem_o = v_ws + 262144;            // (B,H,N,DH)   2,097,152
  float* comb  = mem_o + 2097152;          // (B,N,H*DH)   2,097,152

  dim3 blk(256);
  // QKV projections
  gemm64<0><<<dim3(64, 8), blk, 0, stream>>>(x, Wq, q_ws, nullptr, nullptr, 512, 512);
  gemm64<1><<<dim3(64, 2), blk, 0, stream>>>(x, Wkv, k_ws, v_ws, nullptr, 512, 128);
  // memory attention (HBM-bound: streams 536 MB of mem_kv)
  mem_attn_kernel<<<8192, blk, 0, stream>>>(q_ws, mem_kv, mem_mask, null_k, null_v, mem_o);
  // causal local attention + gated combine
  local_attn_kernel<<<2048, blk, 0, stream>>>(q_ws, k_ws, v_ws, mem_o, gate, comb);
  // output projection + bias
  gemm64<2><<<dim3(64, 8), blk, 0, stream>>>(comb, Wo, out, nullptr, bo, 512, 512);
}

// Round 2
// 888.877 us; speedup vs baseline: 1.8665x; 1.8665x over previous
//
#include <hip/hip_runtime.h>
#include <cstddef>
#include <cstdint>

// Problem constants: B=2, N=2048, DIM=512, H=8, DH=64, K=32, SCALE=1/8
#define SEQ_N  2048
#define NHEAD  8
#define DHEAD  64
#define NMEM   32
#define SCALE_F 0.125f
#define NEG_INF -3.0e38f
#define LDK 72  // padded LDS row stride (ushort units) for 64-wide bf16 tiles

typedef short bf16x8 __attribute__((ext_vector_type(8)));
typedef float f32x4  __attribute__((ext_vector_type(4)));

__device__ __forceinline__ unsigned short f2bf(float f) {
  union { float f; uint32_t u; } v; v.f = f;
  uint32_t u = v.u;
  return (unsigned short)((u + 0x7fffu + ((u >> 16) & 1u)) >> 16);  // RNE
}
__device__ __forceinline__ float bf2f(unsigned short us) {
  union { uint32_t u; float f; } v; v.u = ((uint32_t)us) << 16; return v.f;
}

__device__ __forceinline__ float wred_max(float v) {
#pragma unroll
  for (int o = 32; o > 0; o >>= 1) v = fmaxf(v, __shfl_xor(v, o));
  return v;
}
__device__ __forceinline__ float wred_sum(float v) {
#pragma unroll
  for (int o = 32; o > 0; o >>= 1) v += __shfl_xor(v, o);
  return v;
}

// ---------------------------------------------------------------------------
// Generic 64x64-tile f32 GEMM, 256 threads, 4x4 microtile per thread.
// MODE 0: qb[(b,h,i,d)] = bf16(acc * SCALE)          (rows=b*2048+i, cols=h*64+d)
// MODE 1: cols 0..63 -> kb[r*64+c] bf16; cols 64..127 -> vtb[b][c-64][i] bf16
// MODE 2: Cf[r*512+c] = acc + bias[c]  (f32)
// ---------------------------------------------------------------------------
template <int MODE>
__global__ __launch_bounds__(256) void gemm64(
    const float* __restrict__ A, const float* __restrict__ Bw,
    float* __restrict__ Cf, unsigned short* __restrict__ Ck,
    unsigned short* __restrict__ Cv,
    const float* __restrict__ bias, int Kdim, int Ncols) {
  __shared__ float sA[64][17];
  __shared__ float sB[16][64];
  const int tid = threadIdx.x;
  const int tx = tid & 15, ty = tid >> 4;
  const int rowBase = blockIdx.x * 64, colBase = blockIdx.y * 64;
  float acc[4][4] = {};

  for (int k0 = 0; k0 < Kdim; k0 += 16) {
    {
      int r = tid >> 2, ks = (tid & 3) * 4;
      float4 a4 = *(const float4*)(A + (size_t)(rowBase + r) * Kdim + k0 + ks);
      sA[r][ks + 0] = a4.x; sA[r][ks + 1] = a4.y;
      sA[r][ks + 2] = a4.z; sA[r][ks + 3] = a4.w;
    }
#pragma unroll
    for (int it = 0; it < 4; ++it) {
      int kk = (tid >> 6) + it * 4, c = tid & 63;
      sB[kk][c] = Bw[(size_t)(k0 + kk) * Ncols + colBase + c];
    }
    __syncthreads();
#pragma unroll
    for (int kk = 0; kk < 16; ++kk) {
      float av[4];
#pragma unroll
      for (int u = 0; u < 4; ++u) av[u] = sA[ty * 4 + u][kk];
      float4 b4 = *(const float4*)&sB[kk][tx * 4];
#pragma unroll
      for (int u = 0; u < 4; ++u) {
        acc[u][0] += av[u] * b4.x; acc[u][1] += av[u] * b4.y;
        acc[u][2] += av[u] * b4.z; acc[u][3] += av[u] * b4.w;
      }
    }
    __syncthreads();
  }

#pragma unroll
  for (int ri = 0; ri < 4; ++ri) {
    int r = rowBase + ty * 4 + ri;
#pragma unroll
    for (int ci = 0; ci < 4; ++ci) {
      int c = colBase + tx * 4 + ci;
      float val = acc[ri][ci];
      if (MODE == 0) {
        int b = r >> 11, i = r & 2047, h = c >> 6, d = c & 63;
        Ck[(((size_t)(b * NHEAD + h)) * SEQ_N + i) * DHEAD + d] =
            f2bf(val * SCALE_F);
      } else if (MODE == 1) {
        if (c < DHEAD) {
          Ck[(size_t)r * DHEAD + c] = f2bf(val);
        } else {
          int b = r >> 11, i = r & 2047, d = c - DHEAD;
          Cv[((size_t)b * DHEAD + d) * SEQ_N + i] = f2bf(val);
        }
      } else {
        Cf[(size_t)r * 512 + c] = val + bias[c];
      }
    }
  }
}

// ---------------------------------------------------------------------------
// Memory attention: one wave per (b,h,i) row. 33 keys (null + 32 mem keys).
// q is bf16 and pre-scaled by SCALE, so no extra scale here.
// ---------------------------------------------------------------------------
__global__ __launch_bounds__(256) void mem_attn_kernel(
    const unsigned short* __restrict__ qb, const float* __restrict__ mem_kv,
    const int* __restrict__ mem_mask, const float* __restrict__ null_k,
    const float* __restrict__ null_v, float* __restrict__ mem_out) {
  __shared__ float sq[4][64];
  const int w = threadIdx.x >> 6;
  const int lane = threadIdx.x & 63;
  const int row = blockIdx.x * 4 + w;  // 0 .. B*H*N-1
  const float qv = bf2f(qb[(size_t)row * DHEAD + lane]);  // = q*SCALE
  sq[w][lane] = qv;
  __syncthreads();

  const float* mk = mem_kv + (size_t)row * (NMEM * 2 * DHEAD);

  float nullsim = wred_sum(qv * null_k[lane]);

  float sim = NEG_INF;
  if (lane == 0) {
    sim = nullsim;
  } else if (lane <= NMEM) {
    int j = lane - 1;
    const float4* kp = (const float4*)(mk + j * 2 * DHEAD);
    float s = 0.f;
#pragma unroll
    for (int d4 = 0; d4 < 16; ++d4) {
      float4 k4 = kp[d4];
      float4 q4 = *(const float4*)&sq[w][d4 * 4];
      s += k4.x * q4.x + k4.y * q4.y + k4.z * q4.z + k4.w * q4.w;
    }
    if (mem_mask[(size_t)row * NMEM + j] == 0) s = NEG_INF;
    sim = s;
  }

  float m = wred_max(sim);
  float p = __expf(sim - m);
  if (lane > NMEM) p = 0.f;
  float l = wred_sum(p);
  p /= l;

  float acc = __shfl(p, 0) * null_v[lane];
#pragma unroll
  for (int j = 0; j < NMEM; ++j) {
    float pj = __shfl(p, j + 1);
    acc += pj * mk[j * 2 * DHEAD + DHEAD + lane];
  }
  mem_out[(size_t)row * DHEAD + lane] = acc;
}

// ---------------------------------------------------------------------------
// Causal local attention, MFMA bf16 flash-style + gated combine with mem.
// Block = 256 thr = 4 waves; 64 query rows per block (16 per wave); K-tiles
// of 64 keys. Q pre-scaled bf16. P round-trips through LDS (C-layout ->
// A-layout). V staged transposed so B-frags are contiguous b128 reads.
// MFMA layouts (gfx950, 16x16x32): A[m=lane&15][k=quad*8+j],
// B[k=quad*8+j][n=lane&15], C/D col=lane&15 row=quad*4+reg.
// ---------------------------------------------------------------------------
__global__ __launch_bounds__(256) void local_attn_mfma(
    const unsigned short* __restrict__ qb, const unsigned short* __restrict__ kb,
    const unsigned short* __restrict__ vtb, const float* __restrict__ mem_o,
    const float* __restrict__ gate, float* __restrict__ comb) {
  __shared__ unsigned short sK[64 * LDK];   // [key][depth]
  __shared__ unsigned short sV[64 * LDK];   // [d][key]  (transposed V)
  __shared__ unsigned short sP[4 * 16 * LDK];  // per-wave 16x64 P tile

  const int tid = threadIdx.x;
  const int w = tid >> 6, lane = tid & 63;
  const int m = lane & 15, quad = lane >> 4;
  const int bid = blockIdx.x;
  const int qt = 31 - (bid >> 4);          // heavy q-tiles first
  const int bh = bid & 15;
  const int b = bh >> 3, h = bh & 7;
  const int qbase = qt * 64;

  // Q A-fragments (persist for whole block)
  const unsigned short* qp =
      qb + (((size_t)bh * SEQ_N + qbase + w * 16 + m) * DHEAD) + quad * 8;
  const bf16x8 aq0 = *(const bf16x8*)qp;
  const bf16x8 aq1 = *(const bf16x8*)(qp + 32);

  f32x4 acc[4] = {};                        // [dblk], rows = quad*4+reg
  float mrow[4], lrow[4];
#pragma unroll
  for (int r = 0; r < 4; ++r) { mrow[r] = NEG_INF; lrow[r] = 0.f; }

  unsigned short* sPw = &sP[w * 16 * LDK];

  for (int kt = 0; kt <= qt; ++kt) {
    const int kbase0 = kt * 64;
    __syncthreads();
#pragma unroll
    for (int it = 0; it < 2; ++it) {
      int idx = tid + it * 256;             // 0..511
      int row = idx >> 3, ch = idx & 7;
      *(uint4*)&sK[row * LDK + ch * 8] =
          *(const uint4*)(kb + ((size_t)b * SEQ_N + kbase0 + row) * DHEAD + ch * 8);
      *(uint4*)&sV[row * LDK + ch * 8] =
          *(const uint4*)(vtb + ((size_t)b * DHEAD + row) * SEQ_N + kbase0 + ch * 8);
    }
    __syncthreads();

    // ---- S = Qs · K^T  (16 x 64 per wave) ----
    f32x4 s[4] = {};
#pragma unroll
    for (int nb = 0; nb < 4; ++nb) {
      bf16x8 bk0 = *(const bf16x8*)&sK[(nb * 16 + m) * LDK + quad * 8];
      bf16x8 bk1 = *(const bf16x8*)&sK[(nb * 16 + m) * LDK + 32 + quad * 8];
      s[nb] = __builtin_amdgcn_mfma_f32_16x16x32_bf16(aq0, bk0, s[nb], 0, 0, 0);
      s[nb] = __builtin_amdgcn_mfma_f32_16x16x32_bf16(aq1, bk1, s[nb], 0, 0, 0);
    }

    if (kt == qt) {                         // diagonal tile: causal mask
      int irow0 = w * 16 + quad * 4;
#pragma unroll
      for (int nb = 0; nb < 4; ++nb) {
        int j = nb * 16 + m;
#pragma unroll
        for (int r = 0; r < 4; ++r)
          if (j > irow0 + r) s[nb][r] = NEG_INF;
      }
    }

    // ---- online softmax (per query row; rows live in 16-lane quads) ----
#pragma unroll
    for (int r = 0; r < 4; ++r) {
      float mx = fmaxf(fmaxf(s[0][r], s[1][r]), fmaxf(s[2][r], s[3][r]));
      mx = fmaxf(mx, __shfl_xor(mx, 1));
      mx = fmaxf(mx, __shfl_xor(mx, 2));
      mx = fmaxf(mx, __shfl_xor(mx, 4));
      mx = fmaxf(mx, __shfl_xor(mx, 8));
      float mnew = fmaxf(mrow[r], mx);
      float alpha = __expf(mrow[r] - mnew);
      mrow[r] = mnew;
      float rs = 0.f;
#pragma unroll
      for (int nb = 0; nb < 4; ++nb) {
        float p = __expf(s[nb][r] - mnew);
        s[nb][r] = p;
        rs += p;
      }
      rs += __shfl_xor(rs, 1); rs += __shfl_xor(rs, 2);
      rs += __shfl_xor(rs, 4); rs += __shfl_xor(rs, 8);
      lrow[r] = lrow[r] * alpha + rs;
#pragma unroll
      for (int db = 0; db < 4; ++db) acc[db][r] *= alpha;
    }

    // ---- P (C-layout) -> LDS -> A-layout ----
#pragma unroll
    for (int nb = 0; nb < 4; ++nb)
#pragma unroll
      for (int r = 0; r < 4; ++r)
        sPw[(quad * 4 + r) * LDK + nb * 16 + m] = f2bf(s[nb][r]);

    bf16x8 ap0 = *(const bf16x8*)&sPw[m * LDK + quad * 8];
    bf16x8 ap1 = *(const bf16x8*)&sPw[m * LDK + 32 + quad * 8];

    // ---- O += P · V ----
#pragma unroll
    for (int db = 0; db < 4; ++db) {
      bf16x8 bv0 = *(const bf16x8*)&sV[(db * 16 + m) * LDK + quad * 8];
      bf16x8 bv1 = *(const bf16x8*)&sV[(db * 16 + m) * LDK + 32 + quad * 8];
      acc[db] = __builtin_amdgcn_mfma_f32_16x16x32_bf16(ap0, bv0, acc[db], 0, 0, 0);
      acc[db] = __builtin_amdgcn_mfma_f32_16x16x32_bf16(ap1, bv1, acc[db], 0, 0, 0);
    }
  }

  // ---- epilogue: normalize, gate-combine with memory attention ----
  const float g = 1.f / (1.f + __expf(-gate[h]));
#pragma unroll
  for (int r = 0; r < 4; ++r) {
    int i = qbase + w * 16 + quad * 4 + r;
    float invl = 1.f / lrow[r];
#pragma unroll
    for (int db = 0; db < 4; ++db) {
      int d = db * 16 + m;
      float localv = acc[db][r] * invl;
      float memv = mem_o[((size_t)bh * SEQ_N + i) * DHEAD + d];
      comb[((size_t)(b * SEQ_N + i)) * 512 + h * DHEAD + d] =
          g * localv + (1.f - g) * memv;
    }
  }
}

// ---------------------------------------------------------------------------
extern "C" void kernel_launch(void* const* d_in, const int* in_sizes, int n_in,
                              void* d_out, int out_size, void* d_ws, size_t ws_size,
                              hipStream_t stream) {
  const float* x        = (const float*)d_in[0];
  const float* mem_kv   = (const float*)d_in[1];
  const int*   mem_mask = (const int*)d_in[2];
  const float* Wq       = (const float*)d_in[3];
  const float* Wkv      = (const float*)d_in[4];
  const float* Wo       = (const float*)d_in[5];
  const float* bo       = (const float*)d_in[6];
  const float* null_k   = (const float*)d_in[7];
  const float* null_v   = (const float*)d_in[8];
  const float* gate     = (const float*)d_in[9];
  float* out = (float*)d_out;

  // workspace layout (16B-aligned chunks)
  unsigned short* qb  = (unsigned short*)d_ws;          // (B,H,N,DH) bf16: 4 MB
  unsigned short* kbw = qb + 2097152;                   // (B,N,DH)   bf16: 512 KB
  unsigned short* vtb = kbw + 262144;                   // (B,DH,N)   bf16: 512 KB
  float* mem_o = (float*)(vtb + 262144);                // (B,H,N,DH) f32:  8 MB
  float* comb  = mem_o + 2097152;                       // (B,N,512)  f32:  8 MB

  dim3 blk(256);
  // QKV projections (f32 compute, bf16 outputs for attention)
  gemm64<0><<<dim3(64, 8), blk, 0, stream>>>(x, Wq, nullptr, qb, nullptr, nullptr, 512, 512);
  gemm64<1><<<dim3(64, 2), blk, 0, stream>>>(x, Wkv, nullptr, kbw, vtb, nullptr, 512, 128);
  // memory attention (HBM-bound: streams 536 MB of mem_kv)
  mem_attn_kernel<<<8192, blk, 0, stream>>>(qb, mem_kv, mem_mask, null_k, null_v, mem_o);
  // causal local attention (MFMA) + gated combine
  local_attn_mfma<<<512, blk, 0, stream>>>(qb, kbw, vtb, mem_o, gate, comb);
  // output projection + bias (f32)
  gemm64<2><<<dim3(64, 8), blk, 0, stream>>>(comb, Wo, out, nullptr, nullptr, bo, 512, 512);
}